// Round 3
// baseline (10845.576 us; speedup 1.0000x reference)
//
#include <hip/hip_runtime.h>
#include <hip/hip_bf16.h>
#include <math.h>

#define DD   512
#define NHH  8
#define DHH  64
#define NLL  4
#define NQQ  4
#define CBB  1024
#define DATA 256
#define BB   32
#define TT   512
#define MM   (BB*TT)   // 16384

// ---------------- block reduce ----------------
__device__ __forceinline__ float blk_reduce(float v, float* red) {
    const int t = threadIdx.x;
    red[t] = v;
    __syncthreads();
    #pragma unroll
    for (int s = 128; s > 0; s >>= 1) {
        if (t < s) red[t] += red[t + s];
        __syncthreads();
    }
    float r = red[0];
    __syncthreads();
    return r;
}

// ---------------- positional embedding table ----------------
__global__ __launch_bounds__(256) void pe_k(float* __restrict__ pe) {
    int t = blockIdx.x;      // 512
    int i = threadIdx.x;     // 256 (pairs)
    float dv  = expf((float)(2 * i) * -0.017988946039015984f); // -ln(10000)/512
    float arg = (float)t * dv;
    pe[(size_t)t * DD + 2 * i]     = sinf(arg);
    pe[(size_t)t * DD + 2 * i + 1] = cosf(arg);
}

// ---------------- generic fp32 GEMM, 64x64 tile, 4x4/thread ----------------
enum { EPI_BIAS = 0, EPI_RES = 1, EPI_RELU = 2, EPI_GELU = 3, EPI_PE = 4, EPI_PLAIN = 5 };

template<int EPI, bool BT>
__global__ __launch_bounds__(256)
void gemm_k(const float* __restrict__ A, const float* __restrict__ Bm,
            const float* __restrict__ bias, const float* __restrict__ extra,
            float* __restrict__ Cv, int Mdim, int Ndim, int Kdim)
{
    __shared__ __align__(16) float As[32][68];
    __shared__ __align__(16) float Bs[32][68];
    const int bm = blockIdx.y * 64;
    const int bn = blockIdx.x * 64;
    const int tid = threadIdx.x;
    const int tx = tid & 15, ty = tid >> 4;
    float acc[4][4] = {};
    for (int k0 = 0; k0 < Kdim; k0 += 32) {
        #pragma unroll
        for (int i = 0; i < 2; ++i) {            // A tile 64x32
            int li = tid + i * 256;
            int r = li >> 3;
            int c = (li & 7) << 2;
            float4 v = *(const float4*)(A + (size_t)(bm + r) * Kdim + k0 + c);
            As[c + 0][r] = v.x; As[c + 1][r] = v.y; As[c + 2][r] = v.z; As[c + 3][r] = v.w;
        }
        if (!BT) {
            #pragma unroll
            for (int i = 0; i < 2; ++i) {        // B tile 32x64 (B[K][N])
                int li = tid + i * 256;
                int r = li >> 4;
                int c = (li & 15) << 2;
                float4 v = *(const float4*)(Bm + (size_t)(k0 + r) * Ndim + bn + c);
                *(float4*)&Bs[r][c] = v;
            }
        } else {
            #pragma unroll
            for (int i = 0; i < 2; ++i) {        // B tile from B[N][K] (codebook)
                int li = tid + i * 256;
                int r = li >> 3;                  // n within tile
                int c = (li & 7) << 2;            // k within tile
                float4 v = *(const float4*)(Bm + (size_t)(bn + r) * Kdim + k0 + c);
                Bs[c + 0][r] = v.x; Bs[c + 1][r] = v.y; Bs[c + 2][r] = v.z; Bs[c + 3][r] = v.w;
            }
        }
        __syncthreads();
        #pragma unroll
        for (int k = 0; k < 32; ++k) {
            float4 av = *(const float4*)&As[k][ty * 4];
            float4 bv = *(const float4*)&Bs[k][tx * 4];
            acc[0][0] = fmaf(av.x, bv.x, acc[0][0]); acc[0][1] = fmaf(av.x, bv.y, acc[0][1]);
            acc[0][2] = fmaf(av.x, bv.z, acc[0][2]); acc[0][3] = fmaf(av.x, bv.w, acc[0][3]);
            acc[1][0] = fmaf(av.y, bv.x, acc[1][0]); acc[1][1] = fmaf(av.y, bv.y, acc[1][1]);
            acc[1][2] = fmaf(av.y, bv.z, acc[1][2]); acc[1][3] = fmaf(av.y, bv.w, acc[1][3]);
            acc[2][0] = fmaf(av.z, bv.x, acc[2][0]); acc[2][1] = fmaf(av.z, bv.y, acc[2][1]);
            acc[2][2] = fmaf(av.z, bv.z, acc[2][2]); acc[2][3] = fmaf(av.z, bv.w, acc[2][3]);
            acc[3][0] = fmaf(av.w, bv.x, acc[3][0]); acc[3][1] = fmaf(av.w, bv.y, acc[3][1]);
            acc[3][2] = fmaf(av.w, bv.z, acc[3][2]); acc[3][3] = fmaf(av.w, bv.w, acc[3][3]);
        }
        __syncthreads();
    }
    #pragma unroll
    for (int i = 0; i < 4; ++i) {
        int m = bm + ty * 4 + i;
        #pragma unroll
        for (int j = 0; j < 4; ++j) {
            int n = bn + tx * 4 + j;
            float v = acc[i][j];
            if constexpr (EPI != EPI_PLAIN) v += bias[n];
            if constexpr (EPI == EPI_RES)  v += extra[(size_t)m * Ndim + n];
            if constexpr (EPI == EPI_PE)   v += extra[(size_t)(m & (TT - 1)) * DD + n];
            if constexpr (EPI == EPI_RELU) v = fmaxf(v, 0.0f);
            if constexpr (EPI == EPI_GELU) v = 0.5f * v * (1.0f + erff(v * 0.70710678118654752f));
            Cv[(size_t)m * Ndim + n] = v;
        }
    }
}

// ---------------- fused causal attention: one block per (b, h, 16 q-rows) ----------------
__global__ __launch_bounds__(256)
void attn_k(const float* __restrict__ qkv, float* __restrict__ o)
{
    const int bid = blockIdx.x;
    const int qt = bid & 31;
    const int hh = (bid >> 5) & 7;
    const int bb = bid >> 8;          // batch index WITHIN the chunk
    const int q0 = qt * 16;
    const int tid = threadIdx.x;

    __shared__ __align__(16) float Qs[16][68];
    __shared__ float Ks[64][68];      // [d][kc]
    __shared__ float sc[16][516];
    __shared__ float red[16][17];
    __shared__ float rowmax[16], rowsum[16];

    {   // load Q tile: 16 x 64
        int r = tid >> 4;
        int c = (tid & 15) << 2;
        const float* src = qkv + (size_t)(bb * TT + q0 + r) * (3 * DD) + hh * 64 + c;
        float4 v = *(const float4*)src;
        *(float4*)&Qs[r][c] = v;
    }
    const int kmax = q0 + 16;
    for (int k0 = 0; k0 < kmax; k0 += 64) {
        #pragma unroll
        for (int i = 0; i < 4; ++i) {   // K tile 64x64 -> Ks[d][kc]
            int li = tid + i * 256;
            int kc = li >> 4;
            int c = (li & 15) << 2;
            const float* src = qkv + (size_t)(bb * TT + k0 + kc) * (3 * DD) + DD + hh * 64 + c;
            float4 v = *(const float4*)src;
            Ks[c + 0][kc] = v.x; Ks[c + 1][kc] = v.y; Ks[c + 2][kc] = v.z; Ks[c + 3][kc] = v.w;
        }
        __syncthreads();
        const int kc = tid & 63, qr4 = tid >> 6;
        float s[4] = {0.f, 0.f, 0.f, 0.f};
        #pragma unroll 8
        for (int d = 0; d < 64; ++d) {
            float kv = Ks[d][kc];
            s[0] = fmaf(Qs[qr4 * 4 + 0][d], kv, s[0]);
            s[1] = fmaf(Qs[qr4 * 4 + 1][d], kv, s[1]);
            s[2] = fmaf(Qs[qr4 * 4 + 2][d], kv, s[2]);
            s[3] = fmaf(Qs[qr4 * 4 + 3][d], kv, s[3]);
        }
        int kg = k0 + kc;
        #pragma unroll
        for (int i = 0; i < 4; ++i) {
            int qg = q0 + qr4 * 4 + i;
            sc[qr4 * 4 + i][kg] = (kg <= qg) ? s[i] * 0.125f : -INFINITY;
        }
        __syncthreads();
    }
    // softmax: 16 threads per row
    {
        const int r = tid >> 4, lane = tid & 15;
        const int km = q0 + r + 1;
        float m = -INFINITY;
        for (int k = lane; k < km; k += 16) m = fmaxf(m, sc[r][k]);
        red[r][lane] = m; __syncthreads();
        if (lane == 0) {
            float mm = red[r][0];
            #pragma unroll
            for (int j = 1; j < 16; ++j) mm = fmaxf(mm, red[r][j]);
            rowmax[r] = mm;
        }
        __syncthreads();
        float mm = rowmax[r];
        float ssum = 0.f;
        for (int k = lane; k < km; k += 16) {
            float p = expf(sc[r][k] - mm);
            sc[r][k] = p;
            ssum += p;
        }
        red[r][lane] = ssum; __syncthreads();
        if (lane == 0) {
            float tt = 0.f;
            #pragma unroll
            for (int j = 0; j < 16; ++j) tt += red[r][j];
            rowsum[r] = tt;
        }
        __syncthreads();
    }
    // PV
    {
        const int qr = tid >> 4, dg = tid & 15;
        const int km = q0 + qr + 1;
        float4 acc = {0.f, 0.f, 0.f, 0.f};
        const float* vbase = qkv + (size_t)(bb * TT) * (3 * DD) + 2 * DD + hh * 64 + dg * 4;
        for (int k = 0; k < km; ++k) {
            float p = sc[qr][k];
            float4 v = *(const float4*)(vbase + (size_t)k * (3 * DD));
            acc.x = fmaf(p, v.x, acc.x); acc.y = fmaf(p, v.y, acc.y);
            acc.z = fmaf(p, v.z, acc.z); acc.w = fmaf(p, v.w, acc.w);
        }
        float inv = 1.0f / rowsum[qr];
        acc.x *= inv; acc.y *= inv; acc.z *= inv; acc.w *= inv;
        float* dst = o + (size_t)(bb * TT + q0 + qr) * DD + hh * 64 + dg * 4;
        *(float4*)dst = acc;
    }
}

// ---------------- layernorm over D=512, one block per row ----------------
__global__ __launch_bounds__(256)
void ln_k(const float* __restrict__ src, const float* __restrict__ s,
          const float* __restrict__ b, float* __restrict__ dst)
{
    __shared__ float red[256];
    const int row = blockIdx.x, t = threadIdx.x;
    const size_t base = (size_t)row * DD;
    float x0 = src[base + t], x1 = src[base + 256 + t];
    float mean = blk_reduce(x0 + x1, red) * (1.0f / 512.0f);
    float d0 = x0 - mean, d1 = x1 - mean;
    float var = blk_reduce(d0 * d0 + d1 * d1, red) * (1.0f / 512.0f);
    float inv = 1.0f / sqrtf(var + 1e-5f);
    dst[base + t]       = d0 * inv * s[t] + b[t];
    dst[base + 256 + t] = d1 * inv * s[t + 256] + b[t + 256];
}

// ---------------- codebook squared norms ----------------
__global__ __launch_bounds__(256)
void cn2_k(const float* __restrict__ cb, float* __restrict__ cn2)
{
    __shared__ float red[256];
    const int row = blockIdx.x, t = threadIdx.x;
    float a = cb[(size_t)row * DD + t], b = cb[(size_t)row * DD + 256 + t];
    float tot = blk_reduce(a * a + b * b, red);
    if (t == 0) cn2[row] = tot;
}

// ---------------- argmin over 1024 codes, one block per token ----------------
// d' = cn2[c] - 2*dot  (row-constant ||r||^2 dropped; argmin unchanged)
__global__ __launch_bounds__(256)
void argmin_k(const float* __restrict__ dot, const float* __restrict__ cn2,
              int* __restrict__ idx)
{
    __shared__ float rv[256];
    __shared__ int   ri[256];
    const int row = blockIdx.x, t = threadIdx.x;
    float best = INFINITY; int bi = 0x7fffffff;
    #pragma unroll
    for (int c0 = 0; c0 < CBB; c0 += 256) {
        int c = c0 + t;
        float d = cn2[c] - 2.0f * dot[(size_t)row * CBB + c];
        if (d < best) { best = d; bi = c; }
    }
    rv[t] = best; ri[t] = bi;
    __syncthreads();
    for (int s = 128; s > 0; s >>= 1) {
        if (t < s) {
            if (rv[t + s] < rv[t] || (rv[t + s] == rv[t] && ri[t + s] < ri[t])) {
                rv[t] = rv[t + s]; ri[t] = ri[t + s];
            }
        }
        __syncthreads();
    }
    if (t == 0) idx[row] = ri[0];
}

// ---------------- rotation trick + residual update + loss partial ----------------
__global__ __launch_bounds__(256)
void rotate_k(float* __restrict__ r, const float* __restrict__ cb,
              const int* __restrict__ idx, float* __restrict__ qo,
              float* __restrict__ lp)
{
    __shared__ float red[256];
    const int row = blockIdx.x, t = threadIdx.x;
    const size_t base = (size_t)row * DD;
    const float* qv = cb + (size_t)idx[row] * DD;
    float x0 = r[base + t], x1 = r[base + 256 + t];
    float q0 = qv[t], q1 = qv[t + 256];
    float nx2 = blk_reduce(x0 * x0 + x1 * x1, red);
    float nq2 = blk_reduce(q0 * q0 + q1 * q1, red);
    float dl0 = q0 - x0, dl1 = q1 - x1;
    float ls = blk_reduce(dl0 * dl0 + dl1 * dl1, red);
    if (t == 0) lp[row] = ls;
    const float eps = 1e-6f;
    float nx = sqrtf(nx2), nq = sqrtf(nq2);
    float mx = fmaxf(nx, eps), mq = fmaxf(nq, eps);
    float u0 = x0 / mx, u1 = x1 / mx;
    float qn0 = q0 / mq, qn1 = q1 / mq;
    float w0 = u0 + qn0, w1 = u1 + qn1;
    float nw2 = blk_reduce(w0 * w0 + w1 * w1, red);
    float mw = fmaxf(sqrtf(nw2), eps);
    w0 /= mw; w1 /= mw;
    float xw = blk_reduce(x0 * w0 + x1 * w1, red);
    float xu = blk_reduce(x0 * u0 + x1 * u1, red);
    float scl = nq / mx;
    float o0 = (x0 - 2.0f * xw * w0 + 2.0f * xu * qn0) * scl;
    float o1 = (x1 - 2.0f * xw * w1 + 2.0f * xu * qn1) * scl;
    r[base + t]        = x0 - o0;
    r[base + 256 + t]  = x1 - o1;
    qo[base + t]       += o0;
    qo[base + 256 + t] += o1;
}

// ---------------- commit loss reduce (f32 out) ----------------
__global__ __launch_bounds__(256)
void loss_k(const float* __restrict__ lp, float* __restrict__ out)
{
    __shared__ float red[256];
    const int t = threadIdx.x;
    float cm = 0.f;
    for (int qi = 0; qi < NQQ; ++qi) {
        float s = 0.f;
        for (int i = t; i < MM; i += 256) s += lp[qi * MM + i];
        float tot = blk_reduce(s, red);
        cm += 0.25f * (tot / (float)(MM * DD));
    }
    if (t == 0) out[0] = cm / (float)NQQ;
}

// ---------------- indices -> f32 output ----------------
__global__ __launch_bounds__(256)
void idxout_k(const int* __restrict__ idxw, float* __restrict__ out)
{
    int i = blockIdx.x * 256 + threadIdx.x;   // MM*NQQ = 65536
    int row = i >> 2, qi = i & 3;
    out[i] = (float)idxw[qi * MM + row];
}

// ---------------- host launch ----------------
extern "C" void kernel_launch(void* const* d_in, const int* in_sizes, int n_in,
                              void* d_out, int out_size, void* d_ws, size_t ws_size,
                              hipStream_t stream)
{
    const float* x     = (const float*)d_in[0];
    const float* w_in  = (const float*)d_in[1];
    const float* b_in  = (const float*)d_in[2];
    const float* qkv_w = (const float*)d_in[3];
    const float* qkv_b = (const float*)d_in[4];
    const float* out_w = (const float*)d_in[5];
    const float* out_b = (const float*)d_in[6];
    const float* ln1_s = (const float*)d_in[7];
    const float* ln1_b = (const float*)d_in[8];
    const float* ln2_s = (const float*)d_in[9];
    const float* ln2_b = (const float*)d_in[10];
    const float* ff1_w = (const float*)d_in[11];
    const float* ff1_b = (const float*)d_in[12];
    const float* ff2_w = (const float*)d_in[13];
    const float* ff2_b = (const float*)d_in[14];
    const float* cbs   = (const float*)d_in[15];
    const float* dln_s = (const float*)d_in[16];
    const float* dln_b = (const float*)d_in[17];
    const float* dw1   = (const float*)d_in[18];
    const float* db1   = (const float*)d_in[19];
    const float* dw2   = (const float*)d_in[20];
    const float* db2   = (const float*)d_in[21];

    // ---- workspace layout (fits in ws_size; chunk size adapts) ----
    float* ws  = (float*)d_ws;
    float* pe  = ws;                                   //   262,144 f
    float* h   = pe + (size_t)262144;                  // 8,388,608 f
    float* h2  = h + (size_t)MM * DD;                  // 8,388,608 f
    float* cn2 = h2 + (size_t)MM * DD;                 //     4,096 f
    float* lp  = cn2 + 4096;                           //    65,536 f
    int*   idxw = (int*)(lp + 65536);                  //    65,536 i
    float* C   = (float*)(idxw + 65536);               // chunk scratch

    size_t fixed_bytes = (size_t)((char*)C - (char*)ws);
    size_t cbytes = (ws_size > fixed_bytes) ? ws_size - fixed_bytes : 0;
    // per-batch peak scratch: max(qkv 1536 + atto 512, ffmid 2048, dist 1024) cols
    // = 512 rows * 2048 cols * 4 B = 4 MiB per batch
    int CH = 32;
    while (CH > 1 && (size_t)CH * TT * 2048 * sizeof(float) > cbytes) CH >>= 1;
    const int NC = BB / CH;
    const int CR = CH * TT;            // rows per chunk

    float* qkvc  = C;                          // [CR][1536]
    float* attoc = C + (size_t)CR * 1536;      // [CR][512]
    float* midc  = C;                          // [CR][2048]
    float* distc = C;                          // [CR][1024]
    float* dhc   = C;                          // [CR][512]
    float* dmidc = C + (size_t)CR * DD;        // [CR][512]

    pe_k<<<dim3(512), dim3(256), 0, stream>>>(pe);
    // h = x @ w_in + b_in + pe
    gemm_k<EPI_PE, false><<<dim3(8, 256), 256, 0, stream>>>(x, w_in, b_in, pe, h, MM, DD, DATA);

    for (int l = 0; l < NLL; ++l) {
        for (int c = 0; c < NC; ++c) {
            float* hc  = h  + (size_t)c * CR * DD;
            float* h2c = h2 + (size_t)c * CR * DD;
            gemm_k<EPI_BIAS, false><<<dim3(24, CR / 64), 256, 0, stream>>>(
                hc, qkv_w + (size_t)l * DD * 3 * DD, qkv_b + (size_t)l * 3 * DD,
                nullptr, qkvc, CR, 3 * DD, DD);
            attn_k<<<dim3(CH * 8 * 32), 256, 0, stream>>>(qkvc, attoc);
            gemm_k<EPI_RES, false><<<dim3(8, CR / 64), 256, 0, stream>>>(
                attoc, out_w + (size_t)l * DD * DD, out_b + (size_t)l * DD, hc, h2c, CR, DD, DD);
            ln_k<<<dim3(CR), 256, 0, stream>>>(h2c, ln1_s + (size_t)l * DD, ln1_b + (size_t)l * DD, h2c);
            gemm_k<EPI_RELU, false><<<dim3(32, CR / 64), 256, 0, stream>>>(
                h2c, ff1_w + (size_t)l * DD * 4 * DD, ff1_b + (size_t)l * 4 * DD,
                nullptr, midc, CR, 4 * DD, DD);
            gemm_k<EPI_RES, false><<<dim3(8, CR / 64), 256, 0, stream>>>(
                midc, ff2_w + (size_t)l * 4 * DD * DD, ff2_b + (size_t)l * DD, h2c, hc, CR, DD, 4 * DD);
            ln_k<<<dim3(CR), 256, 0, stream>>>(hc, ln2_s + (size_t)l * DD, ln2_b + (size_t)l * DD, hc);
        }
    }

    // ---- residual VQ: residual lives in h (mutated), quant_out accumulates in h2 ----
    hipMemsetAsync(h2, 0, (size_t)MM * DD * sizeof(float), stream);
    cn2_k<<<dim3(NQQ * CBB), 256, 0, stream>>>(cbs, cn2);
    for (int qi = 0; qi < NQQ; ++qi) {
        for (int c = 0; c < NC; ++c) {
            float* hc = h + (size_t)c * CR * DD;
            gemm_k<EPI_PLAIN, true><<<dim3(16, CR / 64), 256, 0, stream>>>(
                hc, cbs + (size_t)qi * CBB * DD, nullptr, nullptr, distc, CR, CBB, DD);
            argmin_k<<<dim3(CR), 256, 0, stream>>>(distc, cn2 + qi * CBB,
                                                   idxw + qi * MM + (size_t)c * CR);
        }
        rotate_k<<<dim3(MM), 256, 0, stream>>>(h, cbs + (size_t)qi * CBB * DD,
                                               idxw + qi * MM, h2, lp + qi * MM);
    }

    float* outf = (float*)d_out;
    loss_k<<<dim3(1), 256, 0, stream>>>(lp, outf + (size_t)MM * DATA);
    idxout_k<<<dim3(256), 256, 0, stream>>>(idxw, outf + (size_t)MM * DATA + 1);

    // ---- decoder (chunked through C as well) ----
    for (int c = 0; c < NC; ++c) {
        float* h2c = h2 + (size_t)c * CR * DD;
        ln_k<<<dim3(CR), 256, 0, stream>>>(h2c, dln_s, dln_b, dhc);
        gemm_k<EPI_GELU, false><<<dim3(8, CR / 64), 256, 0, stream>>>(
            dhc, dw1, db1, nullptr, dmidc, CR, DD, DD);
        gemm_k<EPI_BIAS, false><<<dim3(4, CR / 64), 256, 0, stream>>>(
            dmidc, dw2, db2, nullptr, outf + (size_t)c * CR * DATA, CR, DATA, DD);
    }
}

// Round 4
// 7899.762 us; speedup vs baseline: 1.3729x; 1.3729x over previous
//
#include <hip/hip_runtime.h>
#include <hip/hip_bf16.h>
#include <math.h>

#define DD   512
#define NHH  8
#define DHH  64
#define NLL  4
#define NQQ  4
#define CBB  1024
#define DATA 256
#define BB   32
#define TT   512
#define MM   (BB*TT)   // 16384

typedef __attribute__((ext_vector_type(8))) short bf16x8;
typedef __attribute__((ext_vector_type(4))) float f32x4;

// ---------------- block reduce ----------------
__device__ __forceinline__ float blk_reduce(float v, float* red) {
    const int t = threadIdx.x;
    red[t] = v;
    __syncthreads();
    #pragma unroll
    for (int s = 128; s > 0; s >>= 1) {
        if (t < s) red[t] += red[t + s];
        __syncthreads();
    }
    float r = red[0];
    __syncthreads();
    return r;
}

// ---------------- positional embedding table ----------------
__global__ __launch_bounds__(256) void pe_k(float* __restrict__ pe) {
    int t = blockIdx.x;      // 512
    int i = threadIdx.x;     // 256 (pairs)
    float dv  = expf((float)(2 * i) * -0.017988946039015984f); // -ln(10000)/512
    float arg = (float)t * dv;
    pe[(size_t)t * DD + 2 * i]     = sinf(arg);
    pe[(size_t)t * DD + 2 * i + 1] = cosf(arg);
}

// ---------------- split fp32 -> 3x bf16 (in-register) ----------------
__device__ __forceinline__ void cvt3x8(const float* v, bf16x8& q0, bf16x8& q1, bf16x8& q2) {
    #pragma unroll
    for (int j = 0; j < 8; ++j) {
        float f = v[j];
        unsigned short h0 = (unsigned short)((__float_as_uint(f) + 0x8000u) >> 16);
        float f0 = __uint_as_float((unsigned)h0 << 16);
        float r1 = f - f0;                       // exact in fp32
        unsigned short h1 = (unsigned short)((__float_as_uint(r1) + 0x8000u) >> 16);
        float f1 = __uint_as_float((unsigned)h1 << 16);
        float r2 = r1 - f1;                      // exact in fp32
        unsigned short h2 = (unsigned short)((__float_as_uint(r2) + 0x8000u) >> 16);
        q0[j] = (short)h0; q1[j] = (short)h1; q2[j] = (short)h2;
    }
}

// ---------------- MFMA GEMM, fp32-accurate via bf16x3 split (6 terms) ----------------
// Tile 128x128, 4 waves, each wave 64x64 = 4x4 frags of 16x16x32.
// A [M][K] fp32. B: BT=false -> [K][N] fp32 ; BT=true -> [N][K] fp32 (codebook).
enum { EPI_BIAS = 0, EPI_RES = 1, EPI_RELU = 2, EPI_GELU = 3, EPI_PE = 4, EPI_PLAIN = 5 };

template<int EPI, bool BT>
__global__ __launch_bounds__(256, 2)
void mgemm_k(const float* __restrict__ A, const float* __restrict__ Bm,
             const float* __restrict__ bias, const float* __restrict__ extra,
             float* __restrict__ Cv, int Mdim, int Ndim, int Kdim)
{
    const int tid = threadIdx.x;
    const int l   = tid & 63;
    const int w   = tid >> 6;
    const int wm0 = blockIdx.y * 128 + (w >> 1) * 64;
    const int wn0 = blockIdx.x * 128 + (w & 1) * 64;
    const int lr  = l & 15;          // row (A) / col (B) within frag
    const int lk  = (l >> 4) * 8;    // k offset within 32

    f32x4 acc[4][4];
    #pragma unroll
    for (int i = 0; i < 4; ++i)
        #pragma unroll
        for (int j = 0; j < 4; ++j)
            acc[i][j] = (f32x4){0.f, 0.f, 0.f, 0.f};

    for (int k0 = 0; k0 < Kdim; k0 += 32) {
        bf16x8 a0[4], a1[4], a2[4];
        #pragma unroll
        for (int mf = 0; mf < 4; ++mf) {
            const float* p = A + (size_t)(wm0 + mf * 16 + lr) * Kdim + k0 + lk;
            float v[8];
            *(float4*)&v[0] = *(const float4*)p;
            *(float4*)&v[4] = *(const float4*)(p + 4);
            cvt3x8(v, a0[mf], a1[mf], a2[mf]);
        }
        #pragma unroll
        for (int nf = 0; nf < 4; ++nf) {
            bf16x8 b0, b1, b2;
            float v[8];
            if constexpr (BT) {
                const float* p = Bm + (size_t)(wn0 + nf * 16 + lr) * Kdim + k0 + lk;
                *(float4*)&v[0] = *(const float4*)p;
                *(float4*)&v[4] = *(const float4*)(p + 4);
            } else {
                const float* p = Bm + (size_t)(k0 + lk) * Ndim + wn0 + nf * 16 + lr;
                #pragma unroll
                for (int j = 0; j < 8; ++j) v[j] = p[(size_t)j * Ndim];
            }
            cvt3x8(v, b0, b1, b2);
            #pragma unroll
            for (int mf = 0; mf < 4; ++mf) {
                f32x4 c = acc[mf][nf];
                c = __builtin_amdgcn_mfma_f32_16x16x32_bf16(a0[mf], b0, c, 0, 0, 0);
                c = __builtin_amdgcn_mfma_f32_16x16x32_bf16(a0[mf], b1, c, 0, 0, 0);
                c = __builtin_amdgcn_mfma_f32_16x16x32_bf16(a1[mf], b0, c, 0, 0, 0);
                c = __builtin_amdgcn_mfma_f32_16x16x32_bf16(a1[mf], b1, c, 0, 0, 0);
                c = __builtin_amdgcn_mfma_f32_16x16x32_bf16(a0[mf], b2, c, 0, 0, 0);
                c = __builtin_amdgcn_mfma_f32_16x16x32_bf16(a2[mf], b0, c, 0, 0, 0);
                acc[mf][nf] = c;
            }
        }
    }

    // epilogue: C/D layout col = l&15, row = (l>>4)*4 + reg   [m89]
    #pragma unroll
    for (int mf = 0; mf < 4; ++mf) {
        #pragma unroll
        for (int r = 0; r < 4; ++r) {
            int m = wm0 + mf * 16 + (l >> 4) * 4 + r;
            #pragma unroll
            for (int nf = 0; nf < 4; ++nf) {
                int n = wn0 + nf * 16 + lr;
                float v = acc[mf][nf][r];
                if constexpr (EPI != EPI_PLAIN) v += bias[n];
                if constexpr (EPI == EPI_RES)  v += extra[(size_t)m * Ndim + n];
                if constexpr (EPI == EPI_PE)   v += extra[(size_t)(m & (TT - 1)) * DD + n];
                if constexpr (EPI == EPI_RELU) v = fmaxf(v, 0.0f);
                if constexpr (EPI == EPI_GELU) v = 0.5f * v * (1.0f + erff(v * 0.70710678118654752f));
                Cv[(size_t)m * Ndim + n] = v;
            }
        }
    }
}

// ---------------- fused causal attention: one block per (b, h, 16 q-rows) ----------------
__global__ __launch_bounds__(256)
void attn_k(const float* __restrict__ qkv, float* __restrict__ o)
{
    const int bid = blockIdx.x;
    const int qt = bid & 31;
    const int hh = (bid >> 5) & 7;
    const int bb = bid >> 8;          // batch index WITHIN the chunk
    const int q0 = qt * 16;
    const int tid = threadIdx.x;

    __shared__ __align__(16) float Qs[16][68];
    __shared__ float Ks[64][68];      // [d][kc]
    __shared__ float sc[16][516];
    __shared__ float red[16][17];
    __shared__ float rowmax[16], rowsum[16];

    {   // load Q tile: 16 x 64
        int r = tid >> 4;
        int c = (tid & 15) << 2;
        const float* src = qkv + (size_t)(bb * TT + q0 + r) * (3 * DD) + hh * 64 + c;
        float4 v = *(const float4*)src;
        *(float4*)&Qs[r][c] = v;
    }
    const int kmax = q0 + 16;
    for (int k0 = 0; k0 < kmax; k0 += 64) {
        #pragma unroll
        for (int i = 0; i < 4; ++i) {   // K tile 64x64 -> Ks[d][kc]
            int li = tid + i * 256;
            int kc = li >> 4;
            int c = (li & 15) << 2;
            const float* src = qkv + (size_t)(bb * TT + k0 + kc) * (3 * DD) + DD + hh * 64 + c;
            float4 v = *(const float4*)src;
            Ks[c + 0][kc] = v.x; Ks[c + 1][kc] = v.y; Ks[c + 2][kc] = v.z; Ks[c + 3][kc] = v.w;
        }
        __syncthreads();
        const int kc = tid & 63, qr4 = tid >> 6;
        float s[4] = {0.f, 0.f, 0.f, 0.f};
        #pragma unroll 8
        for (int d = 0; d < 64; ++d) {
            float kv = Ks[d][kc];
            s[0] = fmaf(Qs[qr4 * 4 + 0][d], kv, s[0]);
            s[1] = fmaf(Qs[qr4 * 4 + 1][d], kv, s[1]);
            s[2] = fmaf(Qs[qr4 * 4 + 2][d], kv, s[2]);
            s[3] = fmaf(Qs[qr4 * 4 + 3][d], kv, s[3]);
        }
        int kg = k0 + kc;
        #pragma unroll
        for (int i = 0; i < 4; ++i) {
            int qg = q0 + qr4 * 4 + i;
            sc[qr4 * 4 + i][kg] = (kg <= qg) ? s[i] * 0.125f : -INFINITY;
        }
        __syncthreads();
    }
    // softmax: 16 threads per row
    {
        const int r = tid >> 4, lane = tid & 15;
        const int km = q0 + r + 1;
        float m = -INFINITY;
        for (int k = lane; k < km; k += 16) m = fmaxf(m, sc[r][k]);
        red[r][lane] = m; __syncthreads();
        if (lane == 0) {
            float mm = red[r][0];
            #pragma unroll
            for (int j = 1; j < 16; ++j) mm = fmaxf(mm, red[r][j]);
            rowmax[r] = mm;
        }
        __syncthreads();
        float mm = rowmax[r];
        float ssum = 0.f;
        for (int k = lane; k < km; k += 16) {
            float p = expf(sc[r][k] - mm);
            sc[r][k] = p;
            ssum += p;
        }
        red[r][lane] = ssum; __syncthreads();
        if (lane == 0) {
            float tt = 0.f;
            #pragma unroll
            for (int j = 0; j < 16; ++j) tt += red[r][j];
            rowsum[r] = tt;
        }
        __syncthreads();
    }
    // PV
    {
        const int qr = tid >> 4, dg = tid & 15;
        const int km = q0 + qr + 1;
        float4 acc = {0.f, 0.f, 0.f, 0.f};
        const float* vbase = qkv + (size_t)(bb * TT) * (3 * DD) + 2 * DD + hh * 64 + dg * 4;
        for (int k = 0; k < km; ++k) {
            float p = sc[qr][k];
            float4 v = *(const float4*)(vbase + (size_t)k * (3 * DD));
            acc.x = fmaf(p, v.x, acc.x); acc.y = fmaf(p, v.y, acc.y);
            acc.z = fmaf(p, v.z, acc.z); acc.w = fmaf(p, v.w, acc.w);
        }
        float inv = 1.0f / rowsum[qr];
        acc.x *= inv; acc.y *= inv; acc.z *= inv; acc.w *= inv;
        float* dst = o + (size_t)(bb * TT + q0 + qr) * DD + hh * 64 + dg * 4;
        *(float4*)dst = acc;
    }
}

// ---------------- layernorm over D=512, one block per row ----------------
__global__ __launch_bounds__(256)
void ln_k(const float* __restrict__ src, const float* __restrict__ s,
          const float* __restrict__ b, float* __restrict__ dst)
{
    __shared__ float red[256];
    const int row = blockIdx.x, t = threadIdx.x;
    const size_t base = (size_t)row * DD;
    float x0 = src[base + t], x1 = src[base + 256 + t];
    float mean = blk_reduce(x0 + x1, red) * (1.0f / 512.0f);
    float d0 = x0 - mean, d1 = x1 - mean;
    float var = blk_reduce(d0 * d0 + d1 * d1, red) * (1.0f / 512.0f);
    float inv = 1.0f / sqrtf(var + 1e-5f);
    dst[base + t]       = d0 * inv * s[t] + b[t];
    dst[base + 256 + t] = d1 * inv * s[t + 256] + b[t + 256];
}

// ---------------- codebook squared norms ----------------
__global__ __launch_bounds__(256)
void cn2_k(const float* __restrict__ cb, float* __restrict__ cn2)
{
    __shared__ float red[256];
    const int row = blockIdx.x, t = threadIdx.x;
    float a = cb[(size_t)row * DD + t], b = cb[(size_t)row * DD + 256 + t];
    float tot = blk_reduce(a * a + b * b, red);
    if (t == 0) cn2[row] = tot;
}

// ---------------- argmin over 1024 codes, one block per token ----------------
// d' = cn2[c] - 2*dot  (row-constant ||r||^2 dropped; argmin unchanged)
__global__ __launch_bounds__(256)
void argmin_k(const float* __restrict__ dot, const float* __restrict__ cn2,
              int* __restrict__ idx)
{
    __shared__ float rv[256];
    __shared__ int   ri[256];
    const int row = blockIdx.x, t = threadIdx.x;
    float best = INFINITY; int bi = 0x7fffffff;
    #pragma unroll
    for (int c0 = 0; c0 < CBB; c0 += 256) {
        int c = c0 + t;
        float d = cn2[c] - 2.0f * dot[(size_t)row * CBB + c];
        if (d < best) { best = d; bi = c; }
    }
    rv[t] = best; ri[t] = bi;
    __syncthreads();
    for (int s = 128; s > 0; s >>= 1) {
        if (t < s) {
            if (rv[t + s] < rv[t] || (rv[t + s] == rv[t] && ri[t + s] < ri[t])) {
                rv[t] = rv[t + s]; ri[t] = ri[t + s];
            }
        }
        __syncthreads();
    }
    if (t == 0) idx[row] = ri[0];
}

// ---------------- rotation trick + residual update + loss partial ----------------
__global__ __launch_bounds__(256)
void rotate_k(float* __restrict__ r, const float* __restrict__ cb,
              const int* __restrict__ idx, float* __restrict__ qo,
              float* __restrict__ lp)
{
    __shared__ float red[256];
    const int row = blockIdx.x, t = threadIdx.x;
    const size_t base = (size_t)row * DD;
    const float* qv = cb + (size_t)idx[row] * DD;
    float x0 = r[base + t], x1 = r[base + 256 + t];
    float q0 = qv[t], q1 = qv[t + 256];
    float nx2 = blk_reduce(x0 * x0 + x1 * x1, red);
    float nq2 = blk_reduce(q0 * q0 + q1 * q1, red);
    float dl0 = q0 - x0, dl1 = q1 - x1;
    float ls = blk_reduce(dl0 * dl0 + dl1 * dl1, red);
    if (t == 0) lp[row] = ls;
    const float eps = 1e-6f;
    float nx = sqrtf(nx2), nq = sqrtf(nq2);
    float mx = fmaxf(nx, eps), mq = fmaxf(nq, eps);
    float u0 = x0 / mx, u1 = x1 / mx;
    float qn0 = q0 / mq, qn1 = q1 / mq;
    float w0 = u0 + qn0, w1 = u1 + qn1;
    float nw2 = blk_reduce(w0 * w0 + w1 * w1, red);
    float mw = fmaxf(sqrtf(nw2), eps);
    w0 /= mw; w1 /= mw;
    float xw = blk_reduce(x0 * w0 + x1 * w1, red);
    float xu = blk_reduce(x0 * u0 + x1 * u1, red);
    float scl = nq / mx;
    float o0 = (x0 - 2.0f * xw * w0 + 2.0f * xu * qn0) * scl;
    float o1 = (x1 - 2.0f * xw * w1 + 2.0f * xu * qn1) * scl;
    r[base + t]        = x0 - o0;
    r[base + 256 + t]  = x1 - o1;
    qo[base + t]       += o0;
    qo[base + 256 + t] += o1;
}

// ---------------- commit loss reduce (f32 out) ----------------
__global__ __launch_bounds__(256)
void loss_k(const float* __restrict__ lp, float* __restrict__ out)
{
    __shared__ float red[256];
    const int t = threadIdx.x;
    float cm = 0.f;
    for (int qi = 0; qi < NQQ; ++qi) {
        float s = 0.f;
        for (int i = t; i < MM; i += 256) s += lp[qi * MM + i];
        float tot = blk_reduce(s, red);
        cm += 0.25f * (tot / (float)(MM * DD));
    }
    if (t == 0) out[0] = cm / (float)NQQ;
}

// ---------------- indices -> f32 output ----------------
__global__ __launch_bounds__(256)
void idxout_k(const int* __restrict__ idxw, float* __restrict__ out)
{
    int i = blockIdx.x * 256 + threadIdx.x;   // MM*NQQ = 65536
    int row = i >> 2, qi = i & 3;
    out[i] = (float)idxw[qi * MM + row];
}

// ---------------- host launch ----------------
extern "C" void kernel_launch(void* const* d_in, const int* in_sizes, int n_in,
                              void* d_out, int out_size, void* d_ws, size_t ws_size,
                              hipStream_t stream)
{
    const float* x     = (const float*)d_in[0];
    const float* w_in  = (const float*)d_in[1];
    const float* b_in  = (const float*)d_in[2];
    const float* qkv_w = (const float*)d_in[3];
    const float* qkv_b = (const float*)d_in[4];
    const float* out_w = (const float*)d_in[5];
    const float* out_b = (const float*)d_in[6];
    const float* ln1_s = (const float*)d_in[7];
    const float* ln1_b = (const float*)d_in[8];
    const float* ln2_s = (const float*)d_in[9];
    const float* ln2_b = (const float*)d_in[10];
    const float* ff1_w = (const float*)d_in[11];
    const float* ff1_b = (const float*)d_in[12];
    const float* ff2_w = (const float*)d_in[13];
    const float* ff2_b = (const float*)d_in[14];
    const float* cbs   = (const float*)d_in[15];
    const float* dln_s = (const float*)d_in[16];
    const float* dln_b = (const float*)d_in[17];
    const float* dw1   = (const float*)d_in[18];
    const float* db1   = (const float*)d_in[19];
    const float* dw2   = (const float*)d_in[20];
    const float* db2   = (const float*)d_in[21];

    // ---- workspace layout (fits in ws_size; chunk size adapts) ----
    float* ws  = (float*)d_ws;
    float* pe  = ws;                                   //   262,144 f
    float* h   = pe + (size_t)262144;                  // 8,388,608 f
    float* h2  = h + (size_t)MM * DD;                  // 8,388,608 f
    float* cn2 = h2 + (size_t)MM * DD;                 //     4,096 f
    float* lp  = cn2 + 4096;                           //    65,536 f
    int*   idxw = (int*)(lp + 65536);                  //    65,536 i
    float* C   = (float*)(idxw + 65536);               // chunk scratch

    size_t fixed_bytes = (size_t)((char*)C - (char*)ws);
    size_t cbytes = (ws_size > fixed_bytes) ? ws_size - fixed_bytes : 0;
    int CH = 32;
    while (CH > 1 && (size_t)CH * TT * 2048 * sizeof(float) > cbytes) CH >>= 1;
    const int NC = BB / CH;
    const int CR = CH * TT;            // rows per chunk

    float* qkvc  = C;                          // [CR][1536]
    float* attoc = C + (size_t)CR * 1536;      // [CR][512]
    float* midc  = C;                          // [CR][2048]
    float* distc = C;                          // [CR][1024]
    float* dhc   = C;                          // [CR][512]
    float* dmidc = C + (size_t)CR * DD;        // [CR][512]

    pe_k<<<dim3(512), dim3(256), 0, stream>>>(pe);
    // h = x @ w_in + b_in + pe
    mgemm_k<EPI_PE, false><<<dim3(4, 128), 256, 0, stream>>>(x, w_in, b_in, pe, h, MM, DD, DATA);

    for (int l = 0; l < NLL; ++l) {
        for (int c = 0; c < NC; ++c) {
            float* hc  = h  + (size_t)c * CR * DD;
            float* h2c = h2 + (size_t)c * CR * DD;
            mgemm_k<EPI_BIAS, false><<<dim3(12, CR / 128), 256, 0, stream>>>(
                hc, qkv_w + (size_t)l * DD * 3 * DD, qkv_b + (size_t)l * 3 * DD,
                nullptr, qkvc, CR, 3 * DD, DD);
            attn_k<<<dim3(CH * 8 * 32), 256, 0, stream>>>(qkvc, attoc);
            mgemm_k<EPI_RES, false><<<dim3(4, CR / 128), 256, 0, stream>>>(
                attoc, out_w + (size_t)l * DD * DD, out_b + (size_t)l * DD, hc, h2c, CR, DD, DD);
            ln_k<<<dim3(CR), 256, 0, stream>>>(h2c, ln1_s + (size_t)l * DD, ln1_b + (size_t)l * DD, h2c);
            mgemm_k<EPI_RELU, false><<<dim3(16, CR / 128), 256, 0, stream>>>(
                h2c, ff1_w + (size_t)l * DD * 4 * DD, ff1_b + (size_t)l * 4 * DD,
                nullptr, midc, CR, 4 * DD, DD);
            mgemm_k<EPI_RES, false><<<dim3(4, CR / 128), 256, 0, stream>>>(
                midc, ff2_w + (size_t)l * 4 * DD * DD, ff2_b + (size_t)l * DD, h2c, hc, CR, DD, 4 * DD);
            ln_k<<<dim3(CR), 256, 0, stream>>>(hc, ln2_s + (size_t)l * DD, ln2_b + (size_t)l * DD, hc);
        }
    }

    // ---- residual VQ: residual lives in h (mutated), quant_out accumulates in h2 ----
    hipMemsetAsync(h2, 0, (size_t)MM * DD * sizeof(float), stream);
    cn2_k<<<dim3(NQQ * CBB), 256, 0, stream>>>(cbs, cn2);
    for (int qi = 0; qi < NQQ; ++qi) {
        for (int c = 0; c < NC; ++c) {
            float* hc = h + (size_t)c * CR * DD;
            mgemm_k<EPI_PLAIN, true><<<dim3(8, CR / 128), 256, 0, stream>>>(
                hc, cbs + (size_t)qi * CBB * DD, nullptr, nullptr, distc, CR, CBB, DD);
            argmin_k<<<dim3(CR), 256, 0, stream>>>(distc, cn2 + qi * CBB,
                                                   idxw + qi * MM + (size_t)c * CR);
        }
        rotate_k<<<dim3(MM), 256, 0, stream>>>(h, cbs + (size_t)qi * CBB * DD,
                                               idxw + qi * MM, h2, lp + qi * MM);
    }

    float* outf = (float*)d_out;
    loss_k<<<dim3(1), 256, 0, stream>>>(lp, outf + (size_t)MM * DATA);
    idxout_k<<<dim3(256), 256, 0, stream>>>(idxw, outf + (size_t)MM * DATA + 1);

    // ---- decoder (chunked through C as well) ----
    for (int c = 0; c < NC; ++c) {
        float* h2c = h2 + (size_t)c * CR * DD;
        ln_k<<<dim3(CR), 256, 0, stream>>>(h2c, dln_s, dln_b, dhc);
        mgemm_k<EPI_GELU, false><<<dim3(4, CR / 128), 256, 0, stream>>>(
            dhc, dw1, db1, nullptr, dmidc, CR, DD, DD);
        mgemm_k<EPI_BIAS, false><<<dim3(2, CR / 128), 256, 0, stream>>>(
            dmidc, dw2, db2, nullptr, outf + (size_t)c * CR * DATA, CR, DATA, DD);
    }
}

// Round 5
// 4957.632 us; speedup vs baseline: 2.1877x; 1.5935x over previous
//
#include <hip/hip_runtime.h>
#include <hip/hip_bf16.h>
#include <math.h>

#define DD   512
#define NHH  8
#define DHH  64
#define NLL  4
#define NQQ  4
#define CBB  1024
#define DATA 256
#define BB   32
#define TT   512
#define MM   (BB*TT)   // 16384

typedef __attribute__((ext_vector_type(8))) short bf16x8;
typedef __attribute__((ext_vector_type(4))) float f32x4;

// ---------------- block reduce ----------------
__device__ __forceinline__ float blk_reduce(float v, float* red) {
    const int t = threadIdx.x;
    red[t] = v;
    __syncthreads();
    #pragma unroll
    for (int s = 128; s > 0; s >>= 1) {
        if (t < s) red[t] += red[t + s];
        __syncthreads();
    }
    float r = red[0];
    __syncthreads();
    return r;
}

// ---------------- positional embedding table ----------------
__global__ __launch_bounds__(256) void pe_k(float* __restrict__ pe) {
    int t = blockIdx.x;      // 512
    int i = threadIdx.x;     // 256 (pairs)
    float dv  = expf((float)(2 * i) * -0.017988946039015984f); // -ln(10000)/512
    float arg = (float)t * dv;
    pe[(size_t)t * DD + 2 * i]     = sinf(arg);
    pe[(size_t)t * DD + 2 * i + 1] = cosf(arg);
}

// ---------------- split fp32 -> 3x bf16 ----------------
__device__ __forceinline__ void cvt3x8(const float* v, bf16x8& q0, bf16x8& q1, bf16x8& q2) {
    #pragma unroll
    for (int j = 0; j < 8; ++j) {
        float f = v[j];
        unsigned short h0 = (unsigned short)((__float_as_uint(f) + 0x8000u) >> 16);
        float f0 = __uint_as_float((unsigned)h0 << 16);
        float r1 = f - f0;
        unsigned short h1 = (unsigned short)((__float_as_uint(r1) + 0x8000u) >> 16);
        float f1 = __uint_as_float((unsigned)h1 << 16);
        float r2 = r1 - f1;
        unsigned short h2 = (unsigned short)((__float_as_uint(r2) + 0x8000u) >> 16);
        q0[j] = (short)h0; q1[j] = (short)h1; q2[j] = (short)h2;
    }
}
__device__ __forceinline__ void cvt3s(float f, short& h0, short& h1, short& h2) {
    unsigned short a0 = (unsigned short)((__float_as_uint(f) + 0x8000u) >> 16);
    float f0 = __uint_as_float((unsigned)a0 << 16);
    float r1 = f - f0;
    unsigned short a1 = (unsigned short)((__float_as_uint(r1) + 0x8000u) >> 16);
    float f1 = __uint_as_float((unsigned)a1 << 16);
    float r2 = r1 - f1;
    unsigned short a2 = (unsigned short)((__float_as_uint(r2) + 0x8000u) >> 16);
    h0 = (short)a0; h1 = (short)a1; h2 = (short)a2;
}

// ---------------- MFMA GEMM, fp32-accurate via bf16x3 split (6 terms) ----------------
enum { EPI_BIAS = 0, EPI_RES = 1, EPI_RELU = 2, EPI_GELU = 3, EPI_PE = 4, EPI_PLAIN = 5 };

template<int EPI, bool BT>
__global__ __launch_bounds__(256, 2)
void mgemm_k(const float* __restrict__ A, const float* __restrict__ Bm,
             const float* __restrict__ bias, const float* __restrict__ extra,
             float* __restrict__ Cv, int Mdim, int Ndim, int Kdim)
{
    const int tid = threadIdx.x;
    const int l   = tid & 63;
    const int w   = tid >> 6;
    const int wm0 = blockIdx.y * 128 + (w >> 1) * 64;
    const int wn0 = blockIdx.x * 128 + (w & 1) * 64;
    const int lr  = l & 15;
    const int lk  = (l >> 4) * 8;

    f32x4 acc[4][4];
    #pragma unroll
    for (int i = 0; i < 4; ++i)
        #pragma unroll
        for (int j = 0; j < 4; ++j)
            acc[i][j] = (f32x4){0.f, 0.f, 0.f, 0.f};

    for (int k0 = 0; k0 < Kdim; k0 += 32) {
        bf16x8 a0[4], a1[4], a2[4];
        #pragma unroll
        for (int mf = 0; mf < 4; ++mf) {
            const float* p = A + (size_t)(wm0 + mf * 16 + lr) * Kdim + k0 + lk;
            float v[8];
            *(float4*)&v[0] = *(const float4*)p;
            *(float4*)&v[4] = *(const float4*)(p + 4);
            cvt3x8(v, a0[mf], a1[mf], a2[mf]);
        }
        #pragma unroll
        for (int nf = 0; nf < 4; ++nf) {
            bf16x8 b0, b1, b2;
            float v[8];
            if constexpr (BT) {
                const float* p = Bm + (size_t)(wn0 + nf * 16 + lr) * Kdim + k0 + lk;
                *(float4*)&v[0] = *(const float4*)p;
                *(float4*)&v[4] = *(const float4*)(p + 4);
            } else {
                const float* p = Bm + (size_t)(k0 + lk) * Ndim + wn0 + nf * 16 + lr;
                #pragma unroll
                for (int j = 0; j < 8; ++j) v[j] = p[(size_t)j * Ndim];
            }
            cvt3x8(v, b0, b1, b2);
            #pragma unroll
            for (int mf = 0; mf < 4; ++mf) {
                f32x4 c = acc[mf][nf];
                c = __builtin_amdgcn_mfma_f32_16x16x32_bf16(a0[mf], b0, c, 0, 0, 0);
                c = __builtin_amdgcn_mfma_f32_16x16x32_bf16(a0[mf], b1, c, 0, 0, 0);
                c = __builtin_amdgcn_mfma_f32_16x16x32_bf16(a1[mf], b0, c, 0, 0, 0);
                c = __builtin_amdgcn_mfma_f32_16x16x32_bf16(a1[mf], b1, c, 0, 0, 0);
                c = __builtin_amdgcn_mfma_f32_16x16x32_bf16(a0[mf], b2, c, 0, 0, 0);
                c = __builtin_amdgcn_mfma_f32_16x16x32_bf16(a2[mf], b0, c, 0, 0, 0);
                acc[mf][nf] = c;
            }
        }
    }

    #pragma unroll
    for (int mf = 0; mf < 4; ++mf) {
        #pragma unroll
        for (int r = 0; r < 4; ++r) {
            int m = wm0 + mf * 16 + (l >> 4) * 4 + r;
            #pragma unroll
            for (int nf = 0; nf < 4; ++nf) {
                int n = wn0 + nf * 16 + lr;
                float v = acc[mf][nf][r];
                if constexpr (EPI != EPI_PLAIN) v += bias[n];
                if constexpr (EPI == EPI_RES)  v += extra[(size_t)m * Ndim + n];
                if constexpr (EPI == EPI_PE)   v += extra[(size_t)(m & (TT - 1)) * DD + n];
                if constexpr (EPI == EPI_RELU) v = fmaxf(v, 0.0f);
                if constexpr (EPI == EPI_GELU) v = 0.5f * v * (1.0f + erff(v * 0.70710678118654752f));
                Cv[(size_t)m * Ndim + n] = v;
            }
        }
    }
}

// ---------------- MFMA flash attention, fp32-accurate via bf16x3 split ----------------
// grid: CH*64 blocks; bid -> qt(8) | hh(8) | bb. 4 waves x 16 q-rows = 64 q-rows/block.
__global__ __launch_bounds__(256, 2)
void mattn_k(const float* __restrict__ qkv, float* __restrict__ o)
{
    const int bid = blockIdx.x;
    const int qt = bid & 7;
    const int hh = (bid >> 3) & 7;
    const int bb = bid >> 6;
    const int tid = threadIdx.x;
    const int w  = tid >> 6;
    const int l  = tid & 63;
    const int lr = l & 15;
    const int lg = l >> 4;
    const int lk = lg * 8;

    __shared__ short Kb[3][4096];   // [plane][(k*64+d) ^ ((k&7)<<3)]  bf16
    __shared__ short Vb[3][4096];   // [plane][(d*64+k) ^ ((d&7)<<3)]  bf16 (transposed)
    __shared__ float Ps[4][1024];   // per-wave P: [(q*64+k) ^ ((q&7)<<3)] fp32

    const float* qbase = qkv + (size_t)bb * TT * 1536 + hh * 64;
    const float* kbase = qbase + DD;
    const float* vbase = qbase + 2 * DD;

    // persistent Q fragments (16 q-rows x 64 d, 3-term split)
    bf16x8 qa[2][3];
    {
        int qrow = qt * 64 + w * 16 + lr;
        #pragma unroll
        for (int dc = 0; dc < 2; ++dc) {
            float v[8];
            const float* p = qbase + (size_t)qrow * 1536 + dc * 32 + lk;
            *(float4*)&v[0] = *(const float4*)p;
            *(float4*)&v[4] = *(const float4*)(p + 4);
            cvt3x8(v, qa[dc][0], qa[dc][1], qa[dc][2]);
        }
    }

    f32x4 oacc[4];
    #pragma unroll
    for (int nf = 0; nf < 4; ++nf) oacc[nf] = (f32x4){0.f, 0.f, 0.f, 0.f};
    float m[4], s[4];
    #pragma unroll
    for (int r = 0; r < 4; ++r) { m[r] = -INFINITY; s[r] = 0.f; }

    for (int kt = 0; kt <= qt; ++kt) {
        __syncthreads();   // previous iteration's LDS reads complete
        // ---- stage K tile (64k x 64d) as 3 bf16 planes ----
        {
            int kr = tid >> 2, dseg = (tid & 3) * 16;
            const float* p = kbase + (size_t)(kt * 64 + kr) * 1536 + dseg;
            float v[16];
            *(float4*)&v[0]  = *(const float4*)p;
            *(float4*)&v[4]  = *(const float4*)(p + 4);
            *(float4*)&v[8]  = *(const float4*)(p + 8);
            *(float4*)&v[12] = *(const float4*)(p + 12);
            bf16x8 t0, t1, t2, u0, u1, u2;
            cvt3x8(v, t0, t1, t2);
            cvt3x8(v + 8, u0, u1, u2);
            int si = (kr * 64 + dseg) ^ ((kr & 7) << 3);
            *(bf16x8*)&Kb[0][si] = t0; *(bf16x8*)&Kb[0][si ^ 8] = u0;
            *(bf16x8*)&Kb[1][si] = t1; *(bf16x8*)&Kb[1][si ^ 8] = u1;
            *(bf16x8*)&Kb[2][si] = t2; *(bf16x8*)&Kb[2][si ^ 8] = u2;
        }
        // ---- stage V tile transposed: Vb[d][k] ----
        {
            int d = tid & 63, kg = (tid >> 6) * 16;
            const float* p = vbase + (size_t)(kt * 64 + kg) * 1536 + d;
            bf16x8 w0[2], w1[2], w2[2];
            #pragma unroll
            for (int i = 0; i < 16; ++i) {
                float f = p[(size_t)i * 1536];
                short h0, h1, h2; cvt3s(f, h0, h1, h2);
                w0[i >> 3][i & 7] = h0; w1[i >> 3][i & 7] = h1; w2[i >> 3][i & 7] = h2;
            }
            int si = (d * 64 + kg) ^ ((d & 7) << 3);
            *(bf16x8*)&Vb[0][si] = w0[0]; *(bf16x8*)&Vb[0][si ^ 8] = w0[1];
            *(bf16x8*)&Vb[1][si] = w1[0]; *(bf16x8*)&Vb[1][si ^ 8] = w1[1];
            *(bf16x8*)&Vb[2][si] = w2[0]; *(bf16x8*)&Vb[2][si ^ 8] = w2[1];
        }
        __syncthreads();

        // ---- QK^T: S (16q x 64k) ----
        f32x4 S4[4];
        #pragma unroll
        for (int nf = 0; nf < 4; ++nf) {
            f32x4 acc = (f32x4){0.f, 0.f, 0.f, 0.f};
            int kcol = nf * 16 + lr;
            int rowx = kcol * 64, sw = (kcol & 7) << 3;
            #pragma unroll
            for (int dc = 0; dc < 2; ++dc) {
                int si = rowx + ((dc * 32 + lk) ^ sw);
                bf16x8 b0 = *(const bf16x8*)&Kb[0][si];
                bf16x8 b1 = *(const bf16x8*)&Kb[1][si];
                bf16x8 b2 = *(const bf16x8*)&Kb[2][si];
                acc = __builtin_amdgcn_mfma_f32_16x16x32_bf16(qa[dc][0], b0, acc, 0, 0, 0);
                acc = __builtin_amdgcn_mfma_f32_16x16x32_bf16(qa[dc][0], b1, acc, 0, 0, 0);
                acc = __builtin_amdgcn_mfma_f32_16x16x32_bf16(qa[dc][1], b0, acc, 0, 0, 0);
                acc = __builtin_amdgcn_mfma_f32_16x16x32_bf16(qa[dc][1], b1, acc, 0, 0, 0);
                acc = __builtin_amdgcn_mfma_f32_16x16x32_bf16(qa[dc][0], b2, acc, 0, 0, 0);
                acc = __builtin_amdgcn_mfma_f32_16x16x32_bf16(qa[dc][2], b0, acc, 0, 0, 0);
            }
            S4[nf] = acc;
        }
        // scale + causal mask (diagonal tile only)
        #pragma unroll
        for (int nf = 0; nf < 4; ++nf)
            #pragma unroll
            for (int r = 0; r < 4; ++r) S4[nf][r] *= 0.125f;
        if (kt == qt) {
            #pragma unroll
            for (int nf = 0; nf < 4; ++nf) {
                int kg_ = nf * 16 + lr;
                #pragma unroll
                for (int r = 0; r < 4; ++r) {
                    int qg_ = w * 16 + lg * 4 + r;
                    if (kg_ > qg_) S4[nf][r] = -INFINITY;
                }
            }
        }
        // ---- online softmax ----
        float mnew[4], scl[4], psum[4];
        #pragma unroll
        for (int r = 0; r < 4; ++r) {
            float v = fmaxf(fmaxf(S4[0][r], S4[1][r]), fmaxf(S4[2][r], S4[3][r]));
            v = fmaxf(v, __shfl_xor(v, 1));
            v = fmaxf(v, __shfl_xor(v, 2));
            v = fmaxf(v, __shfl_xor(v, 4));
            v = fmaxf(v, __shfl_xor(v, 8));
            mnew[r] = fmaxf(m[r], v);
            scl[r] = expf(m[r] - mnew[r]);
            psum[r] = 0.f;
        }
        #pragma unroll
        for (int nf = 0; nf < 4; ++nf) {
            #pragma unroll
            for (int r = 0; r < 4; ++r) {
                float p = expf(S4[nf][r] - mnew[r]);
                int row = lg * 4 + r;
                int col = nf * 16 + lr;
                Ps[w][row * 64 + (col ^ ((row & 7) << 3))] = p;
                psum[r] += p;
            }
        }
        #pragma unroll
        for (int r = 0; r < 4; ++r) {
            float v = psum[r];
            v += __shfl_xor(v, 1);
            v += __shfl_xor(v, 2);
            v += __shfl_xor(v, 4);
            v += __shfl_xor(v, 8);
            s[r] = s[r] * scl[r] + v;
            m[r] = mnew[r];
        }
        #pragma unroll
        for (int nf = 0; nf < 4; ++nf)
            #pragma unroll
            for (int r = 0; r < 4; ++r) oacc[nf][r] *= scl[r];

        // ---- PV: O += P(16x64) . V(64x64) ----
        #pragma unroll
        for (int kc = 0; kc < 2; ++kc) {
            int fi = lr * 64 + ((kc * 32 + lk) ^ ((lr & 7) << 3));
            float pv8[8];
            *(float4*)&pv8[0] = *(const float4*)&Ps[w][fi];
            *(float4*)&pv8[4] = *(const float4*)&Ps[w][fi + 4];
            bf16x8 pa0, pa1, pa2;
            cvt3x8(pv8, pa0, pa1, pa2);
            #pragma unroll
            for (int nf = 0; nf < 4; ++nf) {
                int drow = nf * 16 + lr;
                int si = drow * 64 + ((kc * 32 + lk) ^ ((drow & 7) << 3));
                bf16x8 b0 = *(const bf16x8*)&Vb[0][si];
                bf16x8 b1 = *(const bf16x8*)&Vb[1][si];
                bf16x8 b2 = *(const bf16x8*)&Vb[2][si];
                f32x4 c = oacc[nf];
                c = __builtin_amdgcn_mfma_f32_16x16x32_bf16(pa0, b0, c, 0, 0, 0);
                c = __builtin_amdgcn_mfma_f32_16x16x32_bf16(pa0, b1, c, 0, 0, 0);
                c = __builtin_amdgcn_mfma_f32_16x16x32_bf16(pa1, b0, c, 0, 0, 0);
                c = __builtin_amdgcn_mfma_f32_16x16x32_bf16(pa1, b1, c, 0, 0, 0);
                c = __builtin_amdgcn_mfma_f32_16x16x32_bf16(pa0, b2, c, 0, 0, 0);
                c = __builtin_amdgcn_mfma_f32_16x16x32_bf16(pa2, b0, c, 0, 0, 0);
                oacc[nf] = c;
            }
        }
    }

    // ---- epilogue ----
    #pragma unroll
    for (int nf = 0; nf < 4; ++nf) {
        #pragma unroll
        for (int r = 0; r < 4; ++r) {
            int qrow = qt * 64 + w * 16 + lg * 4 + r;
            o[(size_t)(bb * TT + qrow) * DD + hh * 64 + nf * 16 + lr] = oacc[nf][r] / s[r];
        }
    }
}

// ---------------- layernorm over D=512, one block per row ----------------
__global__ __launch_bounds__(256)
void ln_k(const float* __restrict__ src, const float* __restrict__ s,
          const float* __restrict__ b, float* __restrict__ dst)
{
    __shared__ float red[256];
    const int row = blockIdx.x, t = threadIdx.x;
    const size_t base = (size_t)row * DD;
    float x0 = src[base + t], x1 = src[base + 256 + t];
    float mean = blk_reduce(x0 + x1, red) * (1.0f / 512.0f);
    float d0 = x0 - mean, d1 = x1 - mean;
    float var = blk_reduce(d0 * d0 + d1 * d1, red) * (1.0f / 512.0f);
    float inv = 1.0f / sqrtf(var + 1e-5f);
    dst[base + t]       = d0 * inv * s[t] + b[t];
    dst[base + 256 + t] = d1 * inv * s[t + 256] + b[t + 256];
}

// ---------------- codebook squared norms ----------------
__global__ __launch_bounds__(256)
void cn2_k(const float* __restrict__ cb, float* __restrict__ cn2)
{
    __shared__ float red[256];
    const int row = blockIdx.x, t = threadIdx.x;
    float a = cb[(size_t)row * DD + t], b = cb[(size_t)row * DD + 256 + t];
    float tot = blk_reduce(a * a + b * b, red);
    if (t == 0) cn2[row] = tot;
}

// ---------------- argmin over 1024 codes, one block per token ----------------
__global__ __launch_bounds__(256)
void argmin_k(const float* __restrict__ dot, const float* __restrict__ cn2,
              int* __restrict__ idx)
{
    __shared__ float rv[256];
    __shared__ int   ri[256];
    const int row = blockIdx.x, t = threadIdx.x;
    float best = INFINITY; int bi = 0x7fffffff;
    #pragma unroll
    for (int c0 = 0; c0 < CBB; c0 += 256) {
        int c = c0 + t;
        float d = cn2[c] - 2.0f * dot[(size_t)row * CBB + c];
        if (d < best) { best = d; bi = c; }
    }
    rv[t] = best; ri[t] = bi;
    __syncthreads();
    for (int s = 128; s > 0; s >>= 1) {
        if (t < s) {
            if (rv[t + s] < rv[t] || (rv[t + s] == rv[t] && ri[t + s] < ri[t])) {
                rv[t] = rv[t + s]; ri[t] = ri[t + s];
            }
        }
        __syncthreads();
    }
    if (t == 0) idx[row] = ri[0];
}

// ---------------- rotation trick + residual update + loss partial ----------------
__global__ __launch_bounds__(256)
void rotate_k(float* __restrict__ r, const float* __restrict__ cb,
              const int* __restrict__ idx, float* __restrict__ qo,
              float* __restrict__ lp)
{
    __shared__ float red[256];
    const int row = blockIdx.x, t = threadIdx.x;
    const size_t base = (size_t)row * DD;
    const float* qv = cb + (size_t)idx[row] * DD;
    float x0 = r[base + t], x1 = r[base + 256 + t];
    float q0 = qv[t], q1 = qv[t + 256];
    float nx2 = blk_reduce(x0 * x0 + x1 * x1, red);
    float nq2 = blk_reduce(q0 * q0 + q1 * q1, red);
    float dl0 = q0 - x0, dl1 = q1 - x1;
    float ls = blk_reduce(dl0 * dl0 + dl1 * dl1, red);
    if (t == 0) lp[row] = ls;
    const float eps = 1e-6f;
    float nx = sqrtf(nx2), nq = sqrtf(nq2);
    float mx = fmaxf(nx, eps), mq = fmaxf(nq, eps);
    float u0 = x0 / mx, u1 = x1 / mx;
    float qn0 = q0 / mq, qn1 = q1 / mq;
    float w0 = u0 + qn0, w1 = u1 + qn1;
    float nw2 = blk_reduce(w0 * w0 + w1 * w1, red);
    float mw = fmaxf(sqrtf(nw2), eps);
    w0 /= mw; w1 /= mw;
    float xw = blk_reduce(x0 * w0 + x1 * w1, red);
    float xu = blk_reduce(x0 * u0 + x1 * u1, red);
    float scl = nq / mx;
    float o0 = (x0 - 2.0f * xw * w0 + 2.0f * xu * qn0) * scl;
    float o1 = (x1 - 2.0f * xw * w1 + 2.0f * xu * qn1) * scl;
    r[base + t]        = x0 - o0;
    r[base + 256 + t]  = x1 - o1;
    qo[base + t]       += o0;
    qo[base + 256 + t] += o1;
}

// ---------------- commit loss reduce (f32 out) ----------------
__global__ __launch_bounds__(256)
void loss_k(const float* __restrict__ lp, float* __restrict__ out)
{
    __shared__ float red[256];
    const int t = threadIdx.x;
    float cm = 0.f;
    for (int qi = 0; qi < NQQ; ++qi) {
        float s = 0.f;
        for (int i = t; i < MM; i += 256) s += lp[qi * MM + i];
        float tot = blk_reduce(s, red);
        cm += 0.25f * (tot / (float)(MM * DD));
    }
    if (t == 0) out[0] = cm / (float)NQQ;
}

// ---------------- indices -> f32 output ----------------
__global__ __launch_bounds__(256)
void idxout_k(const int* __restrict__ idxw, float* __restrict__ out)
{
    int i = blockIdx.x * 256 + threadIdx.x;   // MM*NQQ = 65536
    int row = i >> 2, qi = i & 3;
    out[i] = (float)idxw[qi * MM + row];
}

// ---------------- host launch ----------------
extern "C" void kernel_launch(void* const* d_in, const int* in_sizes, int n_in,
                              void* d_out, int out_size, void* d_ws, size_t ws_size,
                              hipStream_t stream)
{
    const float* x     = (const float*)d_in[0];
    const float* w_in  = (const float*)d_in[1];
    const float* b_in  = (const float*)d_in[2];
    const float* qkv_w = (const float*)d_in[3];
    const float* qkv_b = (const float*)d_in[4];
    const float* out_w = (const float*)d_in[5];
    const float* out_b = (const float*)d_in[6];
    const float* ln1_s = (const float*)d_in[7];
    const float* ln1_b = (const float*)d_in[8];
    const float* ln2_s = (const float*)d_in[9];
    const float* ln2_b = (const float*)d_in[10];
    const float* ff1_w = (const float*)d_in[11];
    const float* ff1_b = (const float*)d_in[12];
    const float* ff2_w = (const float*)d_in[13];
    const float* ff2_b = (const float*)d_in[14];
    const float* cbs   = (const float*)d_in[15];
    const float* dln_s = (const float*)d_in[16];
    const float* dln_b = (const float*)d_in[17];
    const float* dw1   = (const float*)d_in[18];
    const float* db1   = (const float*)d_in[19];
    const float* dw2   = (const float*)d_in[20];
    const float* db2   = (const float*)d_in[21];

    float* ws  = (float*)d_ws;
    float* pe  = ws;                                   //   262,144 f
    float* h   = pe + (size_t)262144;                  // 8,388,608 f
    float* h2  = h + (size_t)MM * DD;                  // 8,388,608 f
    float* cn2 = h2 + (size_t)MM * DD;                 //     4,096 f
    float* lp  = cn2 + 4096;                           //    65,536 f
    int*   idxw = (int*)(lp + 65536);                  //    65,536 i
    float* C   = (float*)(idxw + 65536);               // chunk scratch

    size_t fixed_bytes = (size_t)((char*)C - (char*)ws);
    size_t cbytes = (ws_size > fixed_bytes) ? ws_size - fixed_bytes : 0;
    int CH = 32;
    while (CH > 1 && (size_t)CH * TT * 2048 * sizeof(float) > cbytes) CH >>= 1;
    const int NC = BB / CH;
    const int CR = CH * TT;            // rows per chunk

    float* qkvc  = C;                          // [CR][1536]
    float* attoc = C + (size_t)CR * 1536;      // [CR][512]
    float* midc  = C;                          // [CR][2048]
    float* distc = C;                          // [CR][1024]
    float* dhc   = C;                          // [CR][512]
    float* dmidc = C + (size_t)CR * DD;        // [CR][512]

    pe_k<<<dim3(512), dim3(256), 0, stream>>>(pe);
    mgemm_k<EPI_PE, false><<<dim3(4, 128), 256, 0, stream>>>(x, w_in, b_in, pe, h, MM, DD, DATA);

    for (int l = 0; l < NLL; ++l) {
        for (int c = 0; c < NC; ++c) {
            float* hc  = h  + (size_t)c * CR * DD;
            float* h2c = h2 + (size_t)c * CR * DD;
            mgemm_k<EPI_BIAS, false><<<dim3(12, CR / 128), 256, 0, stream>>>(
                hc, qkv_w + (size_t)l * DD * 3 * DD, qkv_b + (size_t)l * 3 * DD,
                nullptr, qkvc, CR, 3 * DD, DD);
            mattn_k<<<dim3(CH * 64), 256, 0, stream>>>(qkvc, attoc);
            mgemm_k<EPI_RES, false><<<dim3(4, CR / 128), 256, 0, stream>>>(
                attoc, out_w + (size_t)l * DD * DD, out_b + (size_t)l * DD, hc, h2c, CR, DD, DD);
            ln_k<<<dim3(CR), 256, 0, stream>>>(h2c, ln1_s + (size_t)l * DD, ln1_b + (size_t)l * DD, h2c);
            mgemm_k<EPI_RELU, false><<<dim3(16, CR / 128), 256, 0, stream>>>(
                h2c, ff1_w + (size_t)l * DD * 4 * DD, ff1_b + (size_t)l * 4 * DD,
                nullptr, midc, CR, 4 * DD, DD);
            mgemm_k<EPI_RES, false><<<dim3(4, CR / 128), 256, 0, stream>>>(
                midc, ff2_w + (size_t)l * 4 * DD * DD, ff2_b + (size_t)l * DD, h2c, hc, CR, DD, 4 * DD);
            ln_k<<<dim3(CR), 256, 0, stream>>>(hc, ln2_s + (size_t)l * DD, ln2_b + (size_t)l * DD, hc);
        }
    }

    hipMemsetAsync(h2, 0, (size_t)MM * DD * sizeof(float), stream);
    cn2_k<<<dim3(NQQ * CBB), 256, 0, stream>>>(cbs, cn2);
    for (int qi = 0; qi < NQQ; ++qi) {
        for (int c = 0; c < NC; ++c) {
            float* hc = h + (size_t)c * CR * DD;
            mgemm_k<EPI_PLAIN, true><<<dim3(8, CR / 128), 256, 0, stream>>>(
                hc, cbs + (size_t)qi * CBB * DD, nullptr, nullptr, distc, CR, CBB, DD);
            argmin_k<<<dim3(CR), 256, 0, stream>>>(distc, cn2 + qi * CBB,
                                                   idxw + qi * MM + (size_t)c * CR);
        }
        rotate_k<<<dim3(MM), 256, 0, stream>>>(h, cbs + (size_t)qi * CBB * DD,
                                               idxw + qi * MM, h2, lp + qi * MM);
    }

    float* outf = (float*)d_out;
    loss_k<<<dim3(1), 256, 0, stream>>>(lp, outf + (size_t)MM * DATA);
    idxout_k<<<dim3(256), 256, 0, stream>>>(idxw, outf + (size_t)MM * DATA + 1);

    for (int c = 0; c < NC; ++c) {
        float* h2c = h2 + (size_t)c * CR * DD;
        ln_k<<<dim3(CR), 256, 0, stream>>>(h2c, dln_s, dln_b, dhc);
        mgemm_k<EPI_GELU, false><<<dim3(4, CR / 128), 256, 0, stream>>>(
            dhc, dw1, db1, nullptr, dmidc, CR, DD, DD);
        mgemm_k<EPI_BIAS, false><<<dim3(2, CR / 128), 256, 0, stream>>>(
            dmidc, dw2, db2, nullptr, outf + (size_t)c * CR * DATA, CR, DATA, DD);
    }
}